// Round 1
// baseline (121.268 us; speedup 1.0000x reference)
//
#include <hip/hip_runtime.h>
#include <hip/hip_bf16.h>
#include <cstdint>

#define ALPHA 0.2f
// B=8, N=1024, Din=Dout=256, M = 8192
// ws layout:
//   WhT bf16 [8][256][1024]   @ 0          (4 MiB)   B^T layout for MFMA B-frags
//   srcE f32 [8192]           @ 4 MiB      (32 KiB)  exp(src)
//   srcF f32 [8192]           @ +32 KiB               exp(ALPHA*src)
//   dstE f32 [8192]           @ +64 KiB               exp(dst)
//   dstF f32 [8192]           @ +96 KiB               exp(ALPHA*dst)
//   mask u64 [8192][16]       @ 4 MiB+128K (1 MiB)   NATURAL packing: bit j&63 of word j>>6

typedef __bf16 bf16_t;
typedef __bf16 bf16x8 __attribute__((ext_vector_type(8)));
typedef float f32x16 __attribute__((ext_vector_type(16)));

// ---------------- Kernel 1: two roles ----------------
// bx < 512 : WhT = bf16(h @ W^T) transposed, via MFMA (unchanged)
// bx >= 512: u = W^T a ; src/dst GEMV -> exp'd factors ; adj -> natural bitmask (16 rows/block)
__global__ __launch_bounds__(256) void k_pre(
    const float* __restrict__ h, const float* __restrict__ W, const float* __restrict__ a,
    const int* __restrict__ adj, bf16_t* __restrict__ WhT,
    float* __restrict__ srcE, float* __restrict__ srcF,
    float* __restrict__ dstE, float* __restrict__ dstF,
    unsigned long long* __restrict__ mask_ws)
{
  __shared__ __align__(16) char smem[64 * 72 * 2 * sizeof(bf16_t)];
  const int bx = blockIdx.x;
  const int t = threadIdx.x;

  if (bx < 512) {
    // ================= GEMM role =================
    bf16_t* WS = (bf16_t*)smem;          // [f_local][d_chunk], stride 72
    bf16_t* HS = WS + 64 * 72;           // [j_local][d_chunk]
    const int b  = bx & 7;
    const int jt = (bx >> 3) & 15;
    const int ft = bx >> 7;
    const int j0 = jt * 64, f0 = ft * 64;
    const int w = t >> 6, lane = t & 63;
    const int mrow = lane & 31, half = lane >> 5;
    const int fsub = (w & 1) * 32, jsub = (w >> 1) * 32;

    const int lr = t >> 2;          // 0..63 (row)
    const int lc = (t & 3) * 16;    // 0,16,32,48 (col group)
    const float* wp = W + ((size_t)(f0 + lr)) * 256 + lc;
    const float* hp = h + ((size_t)(b * 1024 + j0 + lr)) * 256 + lc;

    f32x16 acc;
#pragma unroll
    for (int r = 0; r < 16; r++) acc[r] = 0.f;

    for (int s = 0; s < 4; s++) {
      if (s) __syncthreads();
      {
        float4 w0 = *(const float4*)(wp + s * 64);
        float4 w1 = *(const float4*)(wp + s * 64 + 4);
        float4 w2 = *(const float4*)(wp + s * 64 + 8);
        float4 w3 = *(const float4*)(wp + s * 64 + 12);
        bf16x8 va, vb;
        va[0] = (bf16_t)w0.x; va[1] = (bf16_t)w0.y; va[2] = (bf16_t)w0.z; va[3] = (bf16_t)w0.w;
        va[4] = (bf16_t)w1.x; va[5] = (bf16_t)w1.y; va[6] = (bf16_t)w1.z; va[7] = (bf16_t)w1.w;
        vb[0] = (bf16_t)w2.x; vb[1] = (bf16_t)w2.y; vb[2] = (bf16_t)w2.z; vb[3] = (bf16_t)w2.w;
        vb[4] = (bf16_t)w3.x; vb[5] = (bf16_t)w3.y; vb[6] = (bf16_t)w3.z; vb[7] = (bf16_t)w3.w;
        *(bf16x8*)&WS[lr * 72 + lc] = va;
        *(bf16x8*)&WS[lr * 72 + lc + 8] = vb;
        float4 h0 = *(const float4*)(hp + s * 64);
        float4 h1 = *(const float4*)(hp + s * 64 + 4);
        float4 h2 = *(const float4*)(hp + s * 64 + 8);
        float4 h3 = *(const float4*)(hp + s * 64 + 12);
        bf16x8 vc, vd;
        vc[0] = (bf16_t)h0.x; vc[1] = (bf16_t)h0.y; vc[2] = (bf16_t)h0.z; vc[3] = (bf16_t)h0.w;
        vc[4] = (bf16_t)h1.x; vc[5] = (bf16_t)h1.y; vc[6] = (bf16_t)h1.z; vc[7] = (bf16_t)h1.w;
        vd[0] = (bf16_t)h2.x; vd[1] = (bf16_t)h2.y; vd[2] = (bf16_t)h2.z; vd[3] = (bf16_t)h2.w;
        vd[4] = (bf16_t)h3.x; vd[5] = (bf16_t)h3.y; vd[6] = (bf16_t)h3.z; vd[7] = (bf16_t)h3.w;
        *(bf16x8*)&HS[lr * 72 + lc] = vc;
        *(bf16x8*)&HS[lr * 72 + lc + 8] = vd;
      }
      __syncthreads();
#pragma unroll
      for (int ks = 0; ks < 4; ks++) {
        bf16x8 af = *(const bf16x8*)&WS[(fsub + mrow) * 72 + ks * 16 + half * 8];
        bf16x8 bf = *(const bf16x8*)&HS[(jsub + mrow) * 72 + ks * 16 + half * 8];
        acc = __builtin_amdgcn_mfma_f32_32x32x16_bf16(af, bf, acc, 0, 0, 0);
      }
    }

    // D: col(j)=lane&31, row(f)=(reg&3)+8*(reg>>2)+4*half
    const int jcol = j0 + jsub + mrow;
#pragma unroll
    for (int r = 0; r < 16; r++) {
      int frow = fsub + (r & 3) + 8 * (r >> 2) + 4 * half;
      WhT[(((size_t)(b * 256 + f0 + frow)) << 10) + jcol] = (bf16_t)acc[r];
    }
  } else {
    // ================= PREP role: u, exp factors, natural masks for 16 rows =================
    float* uS = (float*)smem;            // [512]
    const int p  = bx - 512;             // 0..511
    const int m0 = p * 16;
    {
      float s1a = 0.f, s1b = 0.f, s2a = 0.f, s2b = 0.f;
#pragma unroll 4
      for (int f = 0; f < 256; f += 2) {
        float w0 = W[f * 256 + t];
        float w1 = W[(f + 1) * 256 + t];
        s1a = fmaf(w0, a[f], s1a);       s1b = fmaf(w1, a[f + 1], s1b);
        s2a = fmaf(w0, a[256 + f], s2a); s2b = fmaf(w1, a[256 + f + 1], s2b);
      }
      uS[t] = s1a + s1b; uS[256 + t] = s2a + s2b;
    }
    __syncthreads();
    {
      const int n = t >> 4, c = t & 15;
      const int m = m0 + n;
      const float* hp = h + (size_t)m * 256 + c * 16;
      float s1 = 0.f, s2 = 0.f;
#pragma unroll
      for (int i = 0; i < 4; i++) {
        float4 v = *(const float4*)(hp + i * 4);
        const float* u1p = &uS[c * 16 + i * 4];
        const float* u2p = &uS[256 + c * 16 + i * 4];
        s1 = fmaf(v.x, u1p[0], s1); s1 = fmaf(v.y, u1p[1], s1);
        s1 = fmaf(v.z, u1p[2], s1); s1 = fmaf(v.w, u1p[3], s1);
        s2 = fmaf(v.x, u2p[0], s2); s2 = fmaf(v.y, u2p[1], s2);
        s2 = fmaf(v.z, u2p[2], s2); s2 = fmaf(v.w, u2p[3], s2);
      }
#pragma unroll
      for (int off = 8; off; off >>= 1) {
        s1 += __shfl_down(s1, off, 16);
        s2 += __shfl_down(s2, off, 16);
      }
      if (c == 0) {
        srcE[m] = __expf(s1); srcF[m] = __expf(ALPHA * s1);
        dstE[m] = __expf(s2); dstF[m] = __expf(ALPHA * s2);
      }
    }
    // mask build, NATURAL packing: bit j&63 of word j>>6.
    // load k covers cols 256k + t; wave wv ballot -> word 4k+wv, bit = lane.
    {
      const int wv = t >> 6, lane = t & 63;
#pragma unroll 4
      for (int r = 0; r < 16; r++) {
        const size_t row = (size_t)(m0 + r);
        const int* ap = adj + (row << 10) + t;
        unsigned long long b0 = __ballot(ap[0] > 0);
        unsigned long long b1 = __ballot(ap[256] > 0);
        unsigned long long b2 = __ballot(ap[512] > 0);
        unsigned long long b3 = __ballot(ap[768] > 0);
        if (lane == 0) {
          unsigned long long* mp = mask_ws + row * 16 + wv;
          mp[0] = b0; mp[4] = b1; mp[8] = b2; mp[12] = b3;
        }
      }
    }
  }
}

// ---------------- Kernel 2: factored-exp P + MFMA, VALU rowsum normalize ----------------
// 256 blocks = b(8) x itile(32); 512 threads = 8 waves; wave w owns f-tile w*32.
// P-build thread map: ip = t&31 (row), g = t>>5 (16-col group) -> b128 LDS writes,
// broadcast float4 LDS reads. Rowsum accumulated in VALU (replaces the 8x-redundant
// ones-MFMA), reduced once via 2 KiB LDS at the end; epilogue multiplies by 1/rowsum.
__global__ __launch_bounds__(512) void k_attn(
    const bf16_t* __restrict__ WhT,
    const float* __restrict__ srcEg, const float* __restrict__ srcFg,
    const float* __restrict__ dstEg, const float* __restrict__ dstFg,
    const unsigned long long* __restrict__ mask_ws, float* __restrict__ out)
{
  const int b  = blockIdx.x & 7;
  const int i0 = (blockIdx.x >> 3) << 5;
  const int t  = threadIdx.x;            // 0..511
  const int w  = t >> 6;                 // wave 0..7
  const int lane = t & 63;
  const int mrow = lane & 31, half = lane >> 5;
  const int ip = t & 31;                 // P row
  const int g  = t >> 5;                 // col group 0..15

  __shared__ float dstE_s[1024], dstF_s[1024];
  __shared__ unsigned long long maskS[32 * 16];
  __shared__ bf16_t P[2][32 * 264];      // double buffer, stride 264 (conflict-free b128)
  __shared__ float rsS[512];
  __shared__ float rowRcp[32];

  if (t < 256) {
    float4 v = *(const float4*)(dstEg + (b << 10) + t * 4);
    *(float4*)&dstE_s[t * 4] = v;
  } else {
    float4 v = *(const float4*)(dstFg + (b << 10) + (t - 256) * 4);
    *(float4*)&dstF_s[(t - 256) * 4] = v;
  }
  maskS[t] = mask_ws[((size_t)((b << 10) + i0)) * 16 + t];   // exactly 512 words
  const float srcEi = srcEg[(b << 10) + i0 + ip];
  const float srcFi = srcFg[(b << 10) + i0 + ip];
  __syncthreads();

  // mask words for this thread's (row, colgroup), one per c-chunk; 2-op extract later.
  unsigned long long mw[4];
#pragma unroll
  for (int c = 0; c < 4; c++) mw[c] = maskS[ip * 16 + 4 * c + (g >> 2)];
  const int sh = (g & 3) * 16;

  f32x16 acc;
#pragma unroll
  for (int r = 0; r < 16; r++) acc[r] = 0.f;
  float rsA = 0.f, rsB = 0.f;

  // lane's B-frag row: f = w*32 + mrow
  const bf16_t* bp = WhT + (((size_t)(b * 256 + w * 32 + mrow)) << 10);

#pragma unroll
  for (int c = 0; c < 4; c++) {
    bf16_t* Pc = &P[c & 1][0];
    {
      unsigned int m16 = (unsigned int)(mw[c] >> sh);
      float ev[16], fv[16];
      const float* dE = &dstE_s[c * 256 + g * 16];
      const float* dF = &dstF_s[c * 256 + g * 16];
#pragma unroll
      for (int q = 0; q < 4; q++) {
        *(float4*)&ev[q * 4] = *(const float4*)(dE + q * 4);   // broadcast reads
        *(float4*)&fv[q * 4] = *(const float4*)(dF + q * 4);
      }
      bf16x8 v0, v1;
#pragma unroll
      for (int k = 0; k < 16; k++) {
        float pp = srcEi * ev[k];
        float pn = srcFi * fv[k];
        float pv = (pp > 1.0f) ? pp : pn;          // leaky-relu branch via product
        pv = (m16 & (1u << k)) ? pv : 0.0f;        // adjacency mask
        if (k & 1) rsB += pv; else rsA += pv;      // rowsum (replaces ones-MFMA)
        bf16_t pb = (bf16_t)pv;
        if (k < 8) v0[k] = pb; else v1[k - 8] = pb;
      }
      *(bf16x8*)&Pc[ip * 264 + g * 16] = v0;
      *(bf16x8*)&Pc[ip * 264 + g * 16 + 8] = v1;
    }
    __syncthreads();

    const bf16_t* bpc = bp + c * 256 + half * 8;
    const bf16_t* prow = Pc + mrow * 264 + half * 8;
#pragma unroll
    for (int idx = 0; idx < 16; idx++) {
      bf16x8 afr = *(const bf16x8*)(prow + idx * 16);
      bf16x8 bfr = *(const bf16x8*)(bpc + idx * 16);
      acc = __builtin_amdgcn_mfma_f32_32x32x16_bf16(afr, bfr, acc, 0, 0, 0);
    }
  }

  // rowsum reduce: 16 partials per row -> 1/s
  rsS[g * 32 + ip] = rsA + rsB;
  __syncthreads();
  if (t < 32) {
    float s = 0.f;
#pragma unroll
    for (int gg = 0; gg < 16; gg++) s += rsS[gg * 32 + t];
    rowRcp[t] = 1.0f / s;
  }
  __syncthreads();

  // D: col=lane&31, row=(reg&3)+8*(reg>>2)+4*half
  const int col = w * 32 + mrow;
#pragma unroll
  for (int r = 0; r < 16; r++) {
    int row = (r & 3) + 8 * (r >> 2) + 4 * half;
    out[((size_t)((b << 10) + i0 + row)) * 256 + col] = acc[r] * rowRcp[row];
  }
}

// ---------------- Launch ----------------
extern "C" void kernel_launch(void* const* d_in, const int* in_sizes, int n_in,
                              void* d_out, int out_size, void* d_ws, size_t ws_size,
                              hipStream_t stream) {
  const float* h   = (const float*)d_in[0];
  const int*   adj = (const int*)d_in[1];
  const float* W   = (const float*)d_in[2];
  const float* a   = (const float*)d_in[3];
  float* out = (float*)d_out;

  char* wsb = (char*)d_ws;
  bf16_t* WhT = (bf16_t*)wsb;
  float* srcE = (float*)(wsb + (4u << 20));
  float* srcF = srcE + 8192;
  float* dstE = srcF + 8192;
  float* dstF = dstE + 8192;
  unsigned long long* mask_ws = (unsigned long long*)(wsb + (4u << 20) + 131072);

  k_pre <<<1024, 256, 0, stream>>>(h, W, a, adj, WhT, srcE, srcF, dstE, dstF, mask_ws);
  k_attn<<<256,  512, 0, stream>>>(WhT, srcE, srcF, dstE, dstF, mask_ws, out);
}

// Round 2
// 112.537 us; speedup vs baseline: 1.0776x; 1.0776x over previous
//
#include <hip/hip_runtime.h>
#include <hip/hip_bf16.h>
#include <cstdint>

#define ALPHA 0.2f
// B=8, N=1024, Din=Dout=256, M = 8192
// ws layout:
//   WhT bf16 [8][256][1024]   @ 0          (4 MiB)   B^T layout for MFMA B-frags
//   srcE f32 [8192]           @ 4 MiB      (32 KiB)  exp(src)
//   srcF f32 [8192]           @ +32 KiB               exp(ALPHA*src)
//   dstE f32 [8192]           @ +64 KiB               exp(dst)
//   dstF f32 [8192]           @ +96 KiB               exp(ALPHA*dst)
//   mask u64 [8192][16]       @ 4 MiB+128K (1 MiB)   INTERLEAVED packing:
//     word (row, wv*4+kk) bit l = adj[row][256*wv + 4*l + kk]

typedef __bf16 bf16_t;
typedef __bf16 bf16x8 __attribute__((ext_vector_type(8)));
typedef float f32x16 __attribute__((ext_vector_type(16)));

// ---------------- Kernel 1: two roles ----------------
// bx < 512 : WhT = bf16(h @ W^T) transposed, via MFMA (unchanged)
// bx >= 512: u = W^T a (a staged in LDS) ; src/dst GEMV -> exp'd factors ;
//            adj -> interleaved bitmask via int4+ballot (16 rows/block)
__global__ __launch_bounds__(256) void k_pre(
    const float* __restrict__ h, const float* __restrict__ W, const float* __restrict__ a,
    const int* __restrict__ adj, bf16_t* __restrict__ WhT,
    float* __restrict__ srcE, float* __restrict__ srcF,
    float* __restrict__ dstE, float* __restrict__ dstF,
    unsigned long long* __restrict__ mask_ws)
{
  __shared__ __align__(16) char smem[64 * 72 * 2 * sizeof(bf16_t)];
  const int bx = blockIdx.x;
  const int t = threadIdx.x;

  if (bx < 512) {
    // ================= GEMM role =================
    bf16_t* WS = (bf16_t*)smem;          // [f_local][d_chunk], stride 72
    bf16_t* HS = WS + 64 * 72;           // [j_local][d_chunk]
    const int b  = bx & 7;
    const int jt = (bx >> 3) & 15;
    const int ft = bx >> 7;
    const int j0 = jt * 64, f0 = ft * 64;
    const int w = t >> 6, lane = t & 63;
    const int mrow = lane & 31, half = lane >> 5;
    const int fsub = (w & 1) * 32, jsub = (w >> 1) * 32;

    const int lr = t >> 2;          // 0..63 (row)
    const int lc = (t & 3) * 16;    // 0,16,32,48 (col group)
    const float* wp = W + ((size_t)(f0 + lr)) * 256 + lc;
    const float* hp = h + ((size_t)(b * 1024 + j0 + lr)) * 256 + lc;

    f32x16 acc;
#pragma unroll
    for (int r = 0; r < 16; r++) acc[r] = 0.f;

    for (int s = 0; s < 4; s++) {
      if (s) __syncthreads();
      {
        float4 w0 = *(const float4*)(wp + s * 64);
        float4 w1 = *(const float4*)(wp + s * 64 + 4);
        float4 w2 = *(const float4*)(wp + s * 64 + 8);
        float4 w3 = *(const float4*)(wp + s * 64 + 12);
        bf16x8 va, vb;
        va[0] = (bf16_t)w0.x; va[1] = (bf16_t)w0.y; va[2] = (bf16_t)w0.z; va[3] = (bf16_t)w0.w;
        va[4] = (bf16_t)w1.x; va[5] = (bf16_t)w1.y; va[6] = (bf16_t)w1.z; va[7] = (bf16_t)w1.w;
        vb[0] = (bf16_t)w2.x; vb[1] = (bf16_t)w2.y; vb[2] = (bf16_t)w2.z; vb[3] = (bf16_t)w2.w;
        vb[4] = (bf16_t)w3.x; vb[5] = (bf16_t)w3.y; vb[6] = (bf16_t)w3.z; vb[7] = (bf16_t)w3.w;
        *(bf16x8*)&WS[lr * 72 + lc] = va;
        *(bf16x8*)&WS[lr * 72 + lc + 8] = vb;
        float4 h0 = *(const float4*)(hp + s * 64);
        float4 h1 = *(const float4*)(hp + s * 64 + 4);
        float4 h2 = *(const float4*)(hp + s * 64 + 8);
        float4 h3 = *(const float4*)(hp + s * 64 + 12);
        bf16x8 vc, vd;
        vc[0] = (bf16_t)h0.x; vc[1] = (bf16_t)h0.y; vc[2] = (bf16_t)h0.z; vc[3] = (bf16_t)h0.w;
        vc[4] = (bf16_t)h1.x; vc[5] = (bf16_t)h1.y; vc[6] = (bf16_t)h1.z; vc[7] = (bf16_t)h1.w;
        vd[0] = (bf16_t)h2.x; vd[1] = (bf16_t)h2.y; vd[2] = (bf16_t)h2.z; vd[3] = (bf16_t)h2.w;
        vd[4] = (bf16_t)h3.x; vd[5] = (bf16_t)h3.y; vd[6] = (bf16_t)h3.z; vd[7] = (bf16_t)h3.w;
        *(bf16x8*)&HS[lr * 72 + lc] = vc;
        *(bf16x8*)&HS[lr * 72 + lc + 8] = vd;
      }
      __syncthreads();
#pragma unroll
      for (int ks = 0; ks < 4; ks++) {
        bf16x8 af = *(const bf16x8*)&WS[(fsub + mrow) * 72 + ks * 16 + half * 8];
        bf16x8 bf = *(const bf16x8*)&HS[(jsub + mrow) * 72 + ks * 16 + half * 8];
        acc = __builtin_amdgcn_mfma_f32_32x32x16_bf16(af, bf, acc, 0, 0, 0);
      }
    }

    // D: col(j)=lane&31, row(f)=(reg&3)+8*(reg>>2)+4*half
    const int jcol = j0 + jsub + mrow;
#pragma unroll
    for (int r = 0; r < 16; r++) {
      int frow = fsub + (r & 3) + 8 * (r >> 2) + 4 * half;
      WhT[(((size_t)(b * 256 + f0 + frow)) << 10) + jcol] = (bf16_t)acc[r];
    }
  } else {
    // ================= PREP role =================
    float* aS = (float*)smem;            // [512]
    float* uS = aS + 512;                // [512]
    const int p  = bx - 512;             // 0..511
    const int m0 = p * 16;
    aS[t] = a[t];
    aS[t + 256] = a[t + 256];
    __syncthreads();
    {
      float s1 = 0.f, s2 = 0.f;
#pragma unroll 8
      for (int f = 0; f < 256; f++) {
        float w0 = W[f * 256 + t];
        s1 = fmaf(w0, aS[f], s1);
        s2 = fmaf(w0, aS[256 + f], s2);
      }
      uS[t] = s1; uS[256 + t] = s2;
    }
    __syncthreads();
    {
      const int n = t >> 4, c = t & 15;
      const int m = m0 + n;
      const float* hp = h + (size_t)m * 256 + c * 16;
      float s1 = 0.f, s2 = 0.f;
#pragma unroll
      for (int i = 0; i < 4; i++) {
        float4 v = *(const float4*)(hp + i * 4);
        const float* u1p = &uS[c * 16 + i * 4];
        const float* u2p = &uS[256 + c * 16 + i * 4];
        s1 = fmaf(v.x, u1p[0], s1); s1 = fmaf(v.y, u1p[1], s1);
        s1 = fmaf(v.z, u1p[2], s1); s1 = fmaf(v.w, u1p[3], s1);
        s2 = fmaf(v.x, u2p[0], s2); s2 = fmaf(v.y, u2p[1], s2);
        s2 = fmaf(v.z, u2p[2], s2); s2 = fmaf(v.w, u2p[3], s2);
      }
#pragma unroll
      for (int off = 8; off; off >>= 1) {
        s1 += __shfl_down(s1, off, 16);
        s2 += __shfl_down(s2, off, 16);
      }
      if (c == 0) {
        srcE[m] = __expf(s1); srcF[m] = __expf(ALPHA * s1);
        dstE[m] = __expf(s2); dstF[m] = __expf(ALPHA * s2);
      }
    }
    // mask build, INTERLEAVED packing via int4 + 4 ballots (fewest load instrs):
    // word (row, wv*4+kk) bit l = adj[row][256*wv + 4*l + kk]
    {
      const int wv = t >> 6, lane = t & 63;
#pragma unroll 4
      for (int r = 0; r < 16; r++) {
        const size_t row = (size_t)(m0 + r);
        const int4 av = *(const int4*)(adj + (row << 10) + 4 * t);
        unsigned long long b0 = __ballot(av.x > 0);
        unsigned long long b1 = __ballot(av.y > 0);
        unsigned long long b2 = __ballot(av.z > 0);
        unsigned long long b3 = __ballot(av.w > 0);
        if (lane == 0) {
          unsigned long long* mp = mask_ws + row * 16 + wv * 4;
          mp[0] = b0; mp[1] = b1; mp[2] = b2; mp[3] = b3;
        }
      }
    }
  }
}

// ---------------- Kernel 2: factored-exp P + MFMA, VALU rowsum normalize ----------------
// 256 blocks = b(8) x itile(32); 512 threads = 8 waves; wave w owns f-tile w*32.
// B-frags for chunk c prefetched into registers BEFORE P-build(c) so their L2
// latency hides under the VALU P-build instead of stalling the MFMA phase.
// Mask extract (interleaved packing): col jl = g*16+k -> word c*4 + (k&3),
// bit g*4 + (k>>2); 4 pre-shifted words give a 2-op per-element test.
__global__ __launch_bounds__(512) void k_attn(
    const bf16_t* __restrict__ WhT,
    const float* __restrict__ srcEg, const float* __restrict__ srcFg,
    const float* __restrict__ dstEg, const float* __restrict__ dstFg,
    const unsigned long long* __restrict__ mask_ws, float* __restrict__ out)
{
  const int b  = blockIdx.x & 7;
  const int i0 = (blockIdx.x >> 3) << 5;
  const int t  = threadIdx.x;            // 0..511
  const int w  = t >> 6;                 // wave 0..7
  const int lane = t & 63;
  const int mrow = lane & 31, half = lane >> 5;
  const int ip = t & 31;                 // P row
  const int g  = t >> 5;                 // col group 0..15

  __shared__ float dstE_s[1024], dstF_s[1024];
  __shared__ unsigned long long maskS[32 * 16];
  __shared__ bf16_t P[2][32 * 264];      // double buffer, stride 264 (conflict-free b128)
  __shared__ float rsS[512];
  __shared__ float rowRcp[32];

  if (t < 256) {
    float4 v = *(const float4*)(dstEg + (b << 10) + t * 4);
    *(float4*)&dstE_s[t * 4] = v;
  } else {
    float4 v = *(const float4*)(dstFg + (b << 10) + (t - 256) * 4);
    *(float4*)&dstF_s[(t - 256) * 4] = v;
  }
  maskS[t] = mask_ws[((size_t)((b << 10) + i0)) * 16 + t];   // exactly 512 words
  const float srcEi = srcEg[(b << 10) + i0 + ip];
  const float srcFi = srcFg[(b << 10) + i0 + ip];

  // prefetch B-frags for chunk 0 (independent of LDS init; issued before barrier)
  const bf16_t* bp = WhT + (((size_t)(b * 256 + w * 32 + mrow)) << 10) + half * 8;
  bf16x8 bfr[16];
#pragma unroll
  for (int idx = 0; idx < 16; idx++) bfr[idx] = *(const bf16x8*)(bp + idx * 16);

  __syncthreads();

  f32x16 acc;
#pragma unroll
  for (int r = 0; r < 16; r++) acc[r] = 0.f;
  float rsA = 0.f, rsB = 0.f;

#pragma unroll
  for (int c = 0; c < 4; c++) {
    bf16_t* Pc = &P[c & 1][0];
    {
      // 4 pre-shifted mask words for this (row, colgroup, chunk)
      unsigned int q0 = (unsigned int)(maskS[ip * 16 + c * 4 + 0] >> (g * 4));
      unsigned int q1 = (unsigned int)(maskS[ip * 16 + c * 4 + 1] >> (g * 4));
      unsigned int q2 = (unsigned int)(maskS[ip * 16 + c * 4 + 2] >> (g * 4));
      unsigned int q3 = (unsigned int)(maskS[ip * 16 + c * 4 + 3] >> (g * 4));
      float ev[16], fv[16];
      const float* dE = &dstE_s[c * 256 + g * 16];
      const float* dF = &dstF_s[c * 256 + g * 16];
#pragma unroll
      for (int q = 0; q < 4; q++) {
        *(float4*)&ev[q * 4] = *(const float4*)(dE + q * 4);   // broadcast reads
        *(float4*)&fv[q * 4] = *(const float4*)(dF + q * 4);
      }
      bf16x8 v0, v1;
#pragma unroll
      for (int k = 0; k < 16; k++) {
        float pp = srcEi * ev[k];
        float pn = srcFi * fv[k];
        float pv = (pp > 1.0f) ? pp : pn;          // leaky-relu branch via product
        unsigned int sel = ((k & 3) == 0) ? q0 : ((k & 3) == 1) ? q1 : ((k & 3) == 2) ? q2 : q3;
        pv = ((sel >> (k >> 2)) & 1u) ? pv : 0.0f; // adjacency mask
        if (k & 1) rsB += pv; else rsA += pv;      // rowsum (replaces ones-MFMA)
        bf16_t pb = (bf16_t)pv;
        if (k < 8) v0[k] = pb; else v1[k - 8] = pb;
      }
      *(bf16x8*)&Pc[ip * 264 + g * 16] = v0;
      *(bf16x8*)&Pc[ip * 264 + g * 16 + 8] = v1;
    }
    __syncthreads();

    const bf16_t* prow = Pc + mrow * 264 + half * 8;
#pragma unroll
    for (int idx = 0; idx < 16; idx++) {
      bf16x8 afr = *(const bf16x8*)(prow + idx * 16);
      acc = __builtin_amdgcn_mfma_f32_32x32x16_bf16(afr, bfr[idx], acc, 0, 0, 0);
    }
    // prefetch next chunk's B-frags; latency hides under P-build(c+1)
    if (c < 3) {
#pragma unroll
      for (int idx = 0; idx < 16; idx++) bfr[idx] = *(const bf16x8*)(bp + (c + 1) * 256 + idx * 16);
    }
  }

  // rowsum reduce: 16 partials per row -> 1/s
  rsS[g * 32 + ip] = rsA + rsB;
  __syncthreads();
  if (t < 32) {
    float s = 0.f;
#pragma unroll
    for (int gg = 0; gg < 16; gg++) s += rsS[gg * 32 + t];
    rowRcp[t] = 1.0f / s;
  }
  __syncthreads();

  // D: col=lane&31, row=(reg&3)+8*(reg>>2)+4*half
  const int col = w * 32 + mrow;
#pragma unroll
  for (int r = 0; r < 16; r++) {
    int row = (r & 3) + 8 * (r >> 2) + 4 * half;
    out[((size_t)((b << 10) + i0 + row)) * 256 + col] = acc[r] * rowRcp[row];
  }
}

// ---------------- Launch ----------------
extern "C" void kernel_launch(void* const* d_in, const int* in_sizes, int n_in,
                              void* d_out, int out_size, void* d_ws, size_t ws_size,
                              hipStream_t stream) {
  const float* h   = (const float*)d_in[0];
  const int*   adj = (const int*)d_in[1];
  const float* W   = (const float*)d_in[2];
  const float* a   = (const float*)d_in[3];
  float* out = (float*)d_out;

  char* wsb = (char*)d_ws;
  bf16_t* WhT = (bf16_t*)wsb;
  float* srcE = (float*)(wsb + (4u << 20));
  float* srcF = srcE + 8192;
  float* dstE = srcF + 8192;
  float* dstF = dstE + 8192;
  unsigned long long* mask_ws = (unsigned long long*)(wsb + (4u << 20) + 131072);

  k_pre <<<1024, 256, 0, stream>>>(h, W, a, adj, WhT, srcE, srcF, dstE, dstF, mask_ws);
  k_attn<<<256,  512, 0, stream>>>(WhT, srcE, srcF, dstE, dstF, mask_ws, out);
}